// Round 11
// baseline (226.778 us; speedup 1.0000x reference)
//
#include <hip/hip_runtime.h>
#include <hip/hip_cooperative_groups.h>

namespace cg = cooperative_groups;

#define TPB    256   // threads per block (4 waves)
#define QPT    8     // query points per thread (phase 1)
#define SPLIT  32    // database slices per direction
#define QCHUNK 64    // queries per phase-2 block
#define MAXB   64    // max batches supported by phase-3 LDS

// ============================================================================
// ROUND 11: single cooperative kernel. R10's probe attributed only ~9.2 µs of
// R3's 35.6 to the nn inner loop -> ~26 µs is dispatch boundaries + kernel
// ramps + reduce plumbing. Fuse all three stages; grid.sync() replaces the
// two dispatch boundaries. No atomics, fixed-order reductions, deterministic.
//
// Phase 1 (all 512 blocks): directed nn, both directions.
//   block id -> (dir, b, at, split). DB staged as (-2x,-2y,-2z,|t|^2), label
//   poisoning folded (invalid -> coords 0, tn=1e10 == reference BIG).
//   Candidate = pure 3-fma chain; min is over d shifted by |p|^2 (added per
//   query at the end, clamped >= 0). Writes minsplit[dir][b][split][query].
// Phase 2 (512 blocks): per-(dir,b,64-query chunk) min over SPLIT slices,
//   coalesced (lane = query), sqrt + masked sums, wave reduce -> pS/pC.
// Phase 3 (block 0): fixed-order combine -> out[0].
// ============================================================================
__global__ void __launch_bounds__(TPB) fused_kernel(
    const float* __restrict__ pred,
    const float* __restrict__ target,
    const int*   __restrict__ label,
    float* __restrict__ minsplit,     // [2][B][SPLIT][stride]
    float* __restrict__ pS,           // [nred]
    float* __restrict__ pC,           // [nred]
    float* __restrict__ out,
    int B, int N, int M, int natmax, int stride,
    int chunksN, int chunksM, int nred)
{
    cg::grid_group grid = cg::this_grid();
    __shared__ float4 tile[TPB];
    __shared__ float  red[TPB];

    // ---------------- phase 1: nn ----------------
    {
        const int per_dir = B * natmax * SPLIT;
        const int bid = blockIdx.x;
        if (bid < 2 * per_dir) {
            const int dir = bid / per_dir;
            const int r1  = bid - dir * per_dir;
            const int b   = r1 / (natmax * SPLIT);
            const int r2  = r1 - b * (natmax * SPLIT);
            const int at  = r2 / SPLIT;
            const int sp  = r2 - at * SPLIT;

            const float* __restrict__ A  = dir ? target : pred;
            const float* __restrict__ Bp = dir ? pred   : target;
            const int NA = dir ? M : N;
            const int NB = dir ? N : M;
            const int* __restrict__ labB = dir ? label : nullptr;

            const int natiles = (NA + TPB * QPT - 1) / (TPB * QPT);
            if (at < natiles) {
                const size_t abase = (size_t)b * NA;

                float px[QPT], py[QPT], pz[QPT], pn[QPT], best[QPT];
#pragma unroll
                for (int q = 0; q < QPT; ++q) {
                    int a = at * (TPB * QPT) + q * TPB + threadIdx.x;
                    int idx = (a < NA) ? a : 0;
                    const float* spq = A + (abase + idx) * 3;
                    px[q] = spq[0];
                    py[q] = spq[1];
                    pz[q] = spq[2];
                    pn[q] = fmaf(px[q], px[q], fmaf(py[q], py[q], pz[q] * pz[q]));
                    best[q] = 3.0e38f;
                }

                const int slen = (NB + SPLIT - 1) / SPLIT;
                const int sbeg = sp * slen;
                const int send = min(sbeg + slen, NB);
                const size_t bbase = (size_t)b * NB;

                for (int c = sbeg; c < send; c += TPB) {
                    const int cnt = min(send - c, TPB);
                    if (threadIdx.x < cnt) {
                        int m = c + threadIdx.x;
                        const float* spm = Bp + (bbase + m) * 3;
                        float x = spm[0], y = spm[1], z = spm[2];
                        float tn = fmaf(x, x, fmaf(y, y, z * z));
                        if (labB != nullptr && labB[bbase + m] != 1) {
                            x = 0.0f; y = 0.0f; z = 0.0f; tn = 1.0e10f;
                        }
                        tile[threadIdx.x] = make_float4(-2.f * x, -2.f * y, -2.f * z, tn);
                    }
                    __syncthreads();

                    const int jeven = cnt & ~1;
#pragma unroll 8
                    for (int j = 0; j < jeven; j += 2) {
                        float4 t0 = tile[j];      // wave-uniform -> LDS broadcast
                        float4 t1 = tile[j + 1];
#pragma unroll
                        for (int q = 0; q < QPT; ++q) {
                            float v0 = fmaf(px[q], t0.x, fmaf(py[q], t0.y, fmaf(pz[q], t0.z, t0.w)));
                            float v1 = fmaf(px[q], t1.x, fmaf(py[q], t1.y, fmaf(pz[q], t1.z, t1.w)));
                            best[q] = fminf(best[q], fminf(v0, v1));   // -> v_min3_f32
                        }
                    }
                    if (cnt & 1) {
                        float4 t0 = tile[cnt - 1];
#pragma unroll
                        for (int q = 0; q < QPT; ++q) {
                            float v0 = fmaf(px[q], t0.x, fmaf(py[q], t0.y, fmaf(pz[q], t0.z, t0.w)));
                            best[q] = fminf(best[q], v0);
                        }
                    }
                    __syncthreads();
                }

                float* o = minsplit + (((size_t)dir * B + b) * SPLIT + sp) * stride;
#pragma unroll
                for (int q = 0; q < QPT; ++q) {
                    int a = at * (TPB * QPT) + q * TPB + threadIdx.x;
                    if (a < NA) {
                        o[a] = fmaxf(best[q] + pn[q], 0.0f);
                    }
                }
            }
        }
    }

    __threadfence();
    grid.sync();

    // ---------------- phase 2: reduce ----------------
    {
        const int r = blockIdx.x;
        if (r < nred) {
            int dir, b, ch, NA;
            if (r < B * chunksN) { dir = 0; b = r / chunksN; ch = r - b * chunksN; NA = N; }
            else { int r2 = r - B * chunksN; dir = 1; b = r2 / chunksM; ch = r2 - b * chunksM; NA = M; }

            const int lane = threadIdx.x & 63;
            const int sg   = threadIdx.x >> 6;       // slice group 0..3
            const int q    = ch * QCHUNK + lane;

            const float* base = minsplit + ((size_t)(dir * B + b) * SPLIT) * stride + q;

            float m = 3.0e38f;
            if (q < NA) {
#pragma unroll 8
                for (int sp = sg; sp < SPLIT; sp += 4) {
                    m = fminf(m, base[(size_t)sp * stride]);   // coalesced
                }
            }
            red[threadIdx.x] = m;
            __syncthreads();

            if (threadIdx.x < QCHUNK) {
                float mm = fminf(fminf(red[lane], red[64 + lane]),
                                 fminf(red[128 + lane], red[192 + lane]));
                float s = 0.0f, cc = 0.0f;
                if (q < NA) {
                    if (dir == 0) {
                        if (label[(size_t)b * N + q] == 1) { s = sqrtf(mm); cc = 1.0f; }
                    } else {
                        s = sqrtf(mm);
                    }
                }
                for (int off = 32; off > 0; off >>= 1) {   // fixed-order
                    s  += __shfl_down(s, off);
                    cc += __shfl_down(cc, off);
                }
                if (lane == 0) { pS[r] = s; pC[r] = cc; }
            }
        }
    }

    __threadfence();
    grid.sync();

    // ---------------- phase 3: final combine (block 0) ----------------
    if (blockIdx.x == 0) {
        __shared__ float S[2 * MAXB], C[2 * MAXB];
        const int wave = threadIdx.x >> 6;
        const int lane = threadIdx.x & 63;

        for (int p = wave; p < 2 * B; p += 4) {
            const int dir = (p >= B);
            const int b   = dir ? (p - B) : p;
            const int nch = dir ? chunksM : chunksN;
            const int off = dir ? (B * chunksN + b * chunksM) : (b * chunksN);
            float s = 0.0f, cc = 0.0f;
            for (int i = lane; i < nch; i += 64) {
                s  += pS[off + i];
                cc += pC[off + i];
            }
            for (int o = 32; o > 0; o >>= 1) {
                s  += __shfl_down(s, o);
                cc += __shfl_down(cc, o);
            }
            if (lane == 0) { S[p] = s; C[p] = cc; }
        }
        __syncthreads();

        if (threadIdx.x == 0) {
            float acc = 0.0f;
            for (int b = 0; b < B; ++b) {
                float m1 = S[b] / fmaxf(C[b], 1.0f);
                float m2 = S[B + b] / (float)M;
                acc += 0.5f * (m1 + m2);
            }
            out[0] = acc / (float)B;   // * LOSS_WEIGHT (== 1.0)
        }
    }
}

// ---------------------------------------------------------------------------
extern "C" void kernel_launch(void* const* d_in, const int* in_sizes, int n_in,
                              void* d_out, int out_size, void* d_ws, size_t ws_size,
                              hipStream_t stream) {
    const float* pred   = (const float*)d_in[0];  // B*N*3 f32
    const float* target = (const float*)d_in[1];  // B*M*3 f32
    const int*   label  = (const int*)  d_in[2];  // B*N   i32

    int B = in_sizes[3];                 // nums has shape (B,)
    int N = in_sizes[2] / B;             // label is B*N
    int M = in_sizes[1] / (3 * B);       // target is B*M*3

    int stride = (N > M) ? N : M;

    // workspace layout (~4.2 MiB of the provided scratch)
    float* minsplit = (float*)d_ws;                              // 2*B*SPLIT*stride
    int chunksN = (N + QCHUNK - 1) / QCHUNK;
    int chunksM = (M + QCHUNK - 1) / QCHUNK;
    int nred = B * (chunksN + chunksM);
    float* pS = minsplit + (size_t)2 * B * SPLIT * stride;       // nred
    float* pC = pS + nred;                                       // nred
    float* outp = (float*)d_out;

    int nat1 = (N + TPB * QPT - 1) / (TPB * QPT);
    int nat2 = (M + TPB * QPT - 1) / (TPB * QPT);
    int natmax = (nat1 > nat2) ? nat1 : nat2;

    int g_nn   = 2 * B * natmax * SPLIT;   // phase-1 blocks (512 for 4x4096)
    int g_grid = (g_nn > nred) ? g_nn : nred;

    void* args[] = { (void*)&pred, (void*)&target, (void*)&label,
                     (void*)&minsplit, (void*)&pS, (void*)&pC, (void*)&outp,
                     (void*)&B, (void*)&N, (void*)&M, (void*)&natmax,
                     (void*)&stride, (void*)&chunksN, (void*)&chunksM,
                     (void*)&nred };

    hipLaunchCooperativeKernel((const void*)fused_kernel,
                               dim3(g_grid), dim3(TPB), args, 0, stream);
}

// Round 12
// 30.992 us; speedup vs baseline: 7.3173x; 7.3173x over previous
//
#include <hip/hip_runtime.h>

#define TPB   256    // nn threads per block (4 waves)
#define QPT   8      // query points per thread
#define SPLIT 32     // database slices per direction
#define RTPB  256    // reduce threads per block
#define CPB   8      // query chunks per (dir,b) in reduce  -> 2*B*CPB = 64 blocks

// ============================================================================
// ROUND 12: 2 graph nodes (R10 probe: inner loop ~9us; plumbing ~5us; rest is
// per-node overhead -> cut a node). NO cooperative launch (R11: grid.sync
// spilled query arrays, VGPR=36, 227us). Counter/last-block combine kept
// CHEAP: 64 partials, parallel device-scope reads (R4's failure was ~1000
// serial reads).
//
// nn: 512 blocks (2/CU), TPB=256, QPT=8, SPLIT=32 -> per-thread inner shape
// identical to R3's proven loop (128 j x 8 q). DB staged as
// (-2x,-2y,-2z,|t|^2); label poisoning folded (invalid -> coords 0, tn=1e10
// == reference BIG); candidate = pure 3-fma chain; min over it = min over d
// shifted by |p|^2 (added once per query, clamped >= 0). Bit-deterministic.
//
// reduce_final: 64 blocks; each owns (dir, b, 512-query chunk): coalesced
// min over 32 slices, sqrt, masked sums, block reduce -> 1 partial pair;
// atomicExch (device scope) + counter; last block reads the 64 partials in
// parallel (atomic reads -> XCD-coherent) and combines in fixed order.
// ============================================================================

__global__ void __launch_bounds__(TPB) nn_kernel(
    const float* __restrict__ pred,
    const float* __restrict__ target,
    const int*   __restrict__ label,
    float* __restrict__ minsplit,     // [2][B][SPLIT][stride]
    unsigned int* __restrict__ counter,
    int B, int N, int M, int natmax, int stride)
{
    __shared__ float4 tile[TPB];

    if (blockIdx.x == 0 && blockIdx.y == 0 && blockIdx.z == 0 && threadIdx.x == 0) {
        *counter = 0u;   // consumed by reduce_final (next dispatch) each call
    }

    const int dir = blockIdx.z;
    const float* __restrict__ A  = dir ? target : pred;
    const float* __restrict__ Bp = dir ? pred   : target;
    const int NA = dir ? M : N;
    const int NB = dir ? N : M;
    const int* __restrict__ labB = dir ? label : nullptr;

    const int natiles = (NA + TPB * QPT - 1) / (TPB * QPT);
    const int b  = blockIdx.x / natmax;
    const int at = blockIdx.x - b * natmax;
    if (at >= natiles) return;

    const size_t abase = (size_t)b * NA;

    float px[QPT], py[QPT], pz[QPT], pn[QPT], best[QPT];
#pragma unroll
    for (int q = 0; q < QPT; ++q) {
        int a = at * (TPB * QPT) + q * TPB + threadIdx.x;
        int idx = (a < NA) ? a : 0;
        const float* sp = A + (abase + idx) * 3;
        px[q] = sp[0];
        py[q] = sp[1];
        pz[q] = sp[2];
        pn[q] = fmaf(px[q], px[q], fmaf(py[q], py[q], pz[q] * pz[q]));
        best[q] = 3.0e38f;
    }

    const int slen = (NB + SPLIT - 1) / SPLIT;
    const int sbeg = blockIdx.y * slen;
    const int send = min(sbeg + slen, NB);
    const size_t bbase = (size_t)b * NB;

    for (int c = sbeg; c < send; c += TPB) {
        const int cnt = min(send - c, TPB);
        if (threadIdx.x < cnt) {
            int m = c + threadIdx.x;
            const float* sp = Bp + (bbase + m) * 3;
            float x = sp[0], y = sp[1], z = sp[2];
            float tn = fmaf(x, x, fmaf(y, y, z * z));
            if (labB != nullptr && labB[bbase + m] != 1) {   // invalid point
                x = 0.0f; y = 0.0f; z = 0.0f; tn = 1.0e10f;
            }
            tile[threadIdx.x] = make_float4(-2.f * x, -2.f * y, -2.f * z, tn);
        }
        __syncthreads();

        const int jeven = cnt & ~1;
#pragma unroll 8
        for (int j = 0; j < jeven; j += 2) {
            float4 t0 = tile[j];      // wave-uniform -> LDS broadcast
            float4 t1 = tile[j + 1];
#pragma unroll
            for (int q = 0; q < QPT; ++q) {
                float v0 = fmaf(px[q], t0.x, fmaf(py[q], t0.y, fmaf(pz[q], t0.z, t0.w)));
                float v1 = fmaf(px[q], t1.x, fmaf(py[q], t1.y, fmaf(pz[q], t1.z, t1.w)));
                best[q] = fminf(best[q], fminf(v0, v1));   // -> v_min3_f32
            }
        }
        if (cnt & 1) {
            float4 t0 = tile[cnt - 1];
#pragma unroll
            for (int q = 0; q < QPT; ++q) {
                float v0 = fmaf(px[q], t0.x, fmaf(py[q], t0.y, fmaf(pz[q], t0.z, t0.w)));
                best[q] = fminf(best[q], v0);
            }
        }
        __syncthreads();              // protect tile before next stage write
    }

    float* out = minsplit + (((size_t)dir * B + b) * SPLIT + blockIdx.y) * stride;
#pragma unroll
    for (int q = 0; q < QPT; ++q) {
        int a = at * (TPB * QPT) + q * TPB + threadIdx.x;
        if (a < NA) {
            out[a] = fmaxf(best[q] + pn[q], 0.0f);
        }
    }
}

// ---------------------------------------------------------------------------
__device__ __forceinline__ void block_reduce2(float& s, float& cc, float* red) {
    int tid = threadIdx.x;
    red[tid] = s;
    red[RTPB + tid] = cc;
    __syncthreads();
    for (int o = RTPB / 2; o > 0; o >>= 1) {
        if (tid < o) {
            red[tid]        += red[tid + o];
            red[RTPB + tid] += red[RTPB + tid + o];
        }
        __syncthreads();
    }
    s  = red[0];
    cc = red[RTPB];
    __syncthreads();
}

__global__ void __launch_bounds__(RTPB) reduce_final_kernel(
    const float* __restrict__ minsplit,
    const int* __restrict__ label,
    float* __restrict__ pS, float* __restrict__ pC,
    unsigned int* __restrict__ counter,
    float* __restrict__ out,
    int B, int N, int M, int stride, int nblocks)
{
    __shared__ float red[2 * RTPB];
    const int r = blockIdx.x;

    const int dir = r / (B * CPB);
    const int rem = r - dir * (B * CPB);
    const int b   = rem / CPB;
    const int ch  = rem - b * CPB;
    const int NA  = dir ? M : N;
    const int qc  = (NA + CPB - 1) / CPB;          // queries per chunk
    const int qpt = (qc + RTPB - 1) / RTPB;        // queries per thread

    const float* base = minsplit + ((size_t)(dir * B + b) * SPLIT) * stride;

    float s = 0.0f, cc = 0.0f;
    for (int k = 0; k < qpt; ++k) {
        int q = ch * qc + k * RTPB + threadIdx.x;  // consecutive tid -> coalesced
        if (q < min((ch + 1) * qc, NA)) {
            float m = base[q];
#pragma unroll 8
            for (int sp = 1; sp < SPLIT; ++sp) {
                m = fminf(m, base[(size_t)sp * stride + q]);
            }
            if (dir == 0) {
                if (label[(size_t)b * N + q] == 1) { s += sqrtf(m); cc += 1.0f; }
            } else {
                s += sqrtf(m);
            }
        }
    }

    block_reduce2(s, cc, red);

    __shared__ unsigned int is_last;
    if (threadIdx.x == 0) {
        atomicExch(&pS[r], s);                 // device-scope, XCD-coherent
        atomicExch(&pC[r], cc);
        __threadfence();
        unsigned int old = atomicAdd(counter, 1u);
        is_last = (old == (unsigned int)(nblocks - 1)) ? 1u : 0u;
    }
    __syncthreads();

    if (is_last) {
        __shared__ float sS[2 * 64], sC[2 * 64];   // nblocks = 2*B*CPB <= 128 here
        for (int i = threadIdx.x; i < nblocks; i += RTPB) {
            sS[i] = atomicAdd(&pS[i], 0.0f);       // parallel device-scope reads
            sC[i] = atomicAdd(&pC[i], 0.0f);
        }
        __syncthreads();
        if (threadIdx.x == 0) {
            float acc = 0.0f;
            for (int bb = 0; bb < B; ++bb) {
                float S1 = 0.0f, C1 = 0.0f, S2 = 0.0f;
                for (int i = 0; i < CPB; ++i) {
                    S1 += sS[bb * CPB + i];
                    C1 += sC[bb * CPB + i];
                    S2 += sS[B * CPB + bb * CPB + i];
                }
                float m1 = S1 / fmaxf(C1, 1.0f);
                float m2 = S2 / (float)M;
                acc += 0.5f * (m1 + m2);
            }
            out[0] = acc / (float)B;   // * LOSS_WEIGHT (== 1.0)
        }
    }
}

// ---------------------------------------------------------------------------
extern "C" void kernel_launch(void* const* d_in, const int* in_sizes, int n_in,
                              void* d_out, int out_size, void* d_ws, size_t ws_size,
                              hipStream_t stream) {
    const float* pred   = (const float*)d_in[0];  // B*N*3 f32
    const float* target = (const float*)d_in[1];  // B*M*3 f32
    const int*   label  = (const int*)  d_in[2];  // B*N   i32

    const int B = in_sizes[3];                 // nums has shape (B,)
    const int N = in_sizes[2] / B;             // label is B*N
    const int M = in_sizes[1] / (3 * B);       // target is B*M*3

    const int stride = (N > M) ? N : M;

    // workspace layout (~4.2 MiB of the provided scratch)
    float* minsplit = (float*)d_ws;                               // 2*B*SPLIT*stride
    const int nred = 2 * B * CPB;                                 // 64 partials
    float* pS = minsplit + (size_t)2 * B * SPLIT * stride;        // nred
    float* pC = pS + nred;                                        // nred
    unsigned int* counter = (unsigned int*)(pC + nred);

    const int nat1 = (N + TPB * QPT - 1) / (TPB * QPT);
    const int nat2 = (M + TPB * QPT - 1) / (TPB * QPT);
    const int natmax = (nat1 > nat2) ? nat1 : nat2;
    dim3 g(B * natmax, SPLIT, 2);
    nn_kernel<<<g, TPB, 0, stream>>>(pred, target, label, minsplit, counter,
                                     B, N, M, natmax, stride);

    reduce_final_kernel<<<nred, RTPB, 0, stream>>>(minsplit, label, pS, pC,
                                                   counter, (float*)d_out,
                                                   B, N, M, stride, nred);
}

// Round 13
// 30.770 us; speedup vs baseline: 7.3700x; 1.0072x over previous
//
#include <hip/hip_runtime.h>

#define TPB   256    // nn threads per block (4 waves)
#define QPT   8      // query points per thread
#define SPLIT 32     // database slices per direction
#define RTPB  256    // reduce threads per block
#define CPB   8      // query chunks per (dir,b) in reduce  -> 2*B*CPB = 64 blocks

typedef float f32x2 __attribute__((ext_vector_type(2)));

// ============================================================================
// ROUND 13 = R12 (best: 31.0 us) with a packed-f32 inner loop.
// DB slice staged SoA (xs/ys/zs/tn) so j-PAIRS load as f32x2 (ds_read_b64);
// candidate for 2 DB points computed with 3 x v_pk_fma_f32 + 1 x v_pk_min_f32
// via __builtin_elementwise_{fma,min} vector IR -> 2 instr/pair-op (was 4).
// Pair-lane min fold at the end is exact (fp min associative, no NaN) ->
// bit-identical result. All else verbatim R12.
// ============================================================================

__global__ void __launch_bounds__(TPB) nn_kernel(
    const float* __restrict__ pred,
    const float* __restrict__ target,
    const int*   __restrict__ label,
    float* __restrict__ minsplit,     // [2][B][SPLIT][stride]
    unsigned int* __restrict__ counter,
    int B, int N, int M, int natmax, int stride)
{
    __shared__ float xs[TPB], ys[TPB], zs[TPB], ws[TPB];

    if (blockIdx.x == 0 && blockIdx.y == 0 && blockIdx.z == 0 && threadIdx.x == 0) {
        *counter = 0u;   // consumed by reduce_final (next dispatch) each call
    }

    const int dir = blockIdx.z;
    const float* __restrict__ A  = dir ? target : pred;
    const float* __restrict__ Bp = dir ? pred   : target;
    const int NA = dir ? M : N;
    const int NB = dir ? N : M;
    const int* __restrict__ labB = dir ? label : nullptr;

    const int natiles = (NA + TPB * QPT - 1) / (TPB * QPT);
    const int b  = blockIdx.x / natmax;
    const int at = blockIdx.x - b * natmax;
    if (at >= natiles) return;

    const size_t abase = (size_t)b * NA;

    float px[QPT], py[QPT], pz[QPT], pn[QPT];
    f32x2 best2[QPT];
#pragma unroll
    for (int q = 0; q < QPT; ++q) {
        int a = at * (TPB * QPT) + q * TPB + threadIdx.x;
        int idx = (a < NA) ? a : 0;
        const float* sp = A + (abase + idx) * 3;
        px[q] = sp[0];
        py[q] = sp[1];
        pz[q] = sp[2];
        pn[q] = fmaf(px[q], px[q], fmaf(py[q], py[q], pz[q] * pz[q]));
        best2[q] = (f32x2){3.0e38f, 3.0e38f};
    }

    const int slen = (NB + SPLIT - 1) / SPLIT;
    const int sbeg = blockIdx.y * slen;
    const int send = min(sbeg + slen, NB);
    const size_t bbase = (size_t)b * NB;

    for (int c = sbeg; c < send; c += TPB) {
        const int cnt = min(send - c, TPB);
        if (threadIdx.x < cnt) {
            int m = c + threadIdx.x;
            const float* sp = Bp + (bbase + m) * 3;
            float x = sp[0], y = sp[1], z = sp[2];
            float tn = fmaf(x, x, fmaf(y, y, z * z));
            if (labB != nullptr && labB[bbase + m] != 1) {   // invalid point
                x = 0.0f; y = 0.0f; z = 0.0f; tn = 1.0e10f;
            }
            xs[threadIdx.x] = -2.0f * x;
            ys[threadIdx.x] = -2.0f * y;
            zs[threadIdx.x] = -2.0f * z;
            ws[threadIdx.x] = tn;
        }
        __syncthreads();

        const int npair = cnt >> 1;
#pragma unroll 4
        for (int jp = 0; jp < npair; ++jp) {
            // wave-uniform SoA pair loads (ds_read_b64 broadcast)
            f32x2 tx = *reinterpret_cast<const f32x2*>(&xs[2 * jp]);
            f32x2 ty = *reinterpret_cast<const f32x2*>(&ys[2 * jp]);
            f32x2 tz = *reinterpret_cast<const f32x2*>(&zs[2 * jp]);
            f32x2 tw = *reinterpret_cast<const f32x2*>(&ws[2 * jp]);
#pragma unroll
            for (int q = 0; q < QPT; ++q) {
                f32x2 vx = {px[q], px[q]};
                f32x2 vy = {py[q], py[q]};
                f32x2 vz = {pz[q], pz[q]};
                f32x2 v = __builtin_elementwise_fma(vx, tx,
                          __builtin_elementwise_fma(vy, ty,
                          __builtin_elementwise_fma(vz, tz, tw)));
                best2[q] = __builtin_elementwise_min(best2[q], v);  // v_pk_min
            }
        }
        if (cnt & 1) {
            float tx = xs[cnt - 1], ty = ys[cnt - 1], tz = zs[cnt - 1], tw = ws[cnt - 1];
#pragma unroll
            for (int q = 0; q < QPT; ++q) {
                float v = fmaf(px[q], tx, fmaf(py[q], ty, fmaf(pz[q], tz, tw)));
                best2[q].x = fminf(best2[q].x, v);
            }
        }
        __syncthreads();              // protect SoA tile before next stage
    }

    float* out = minsplit + (((size_t)dir * B + b) * SPLIT + blockIdx.y) * stride;
#pragma unroll
    for (int q = 0; q < QPT; ++q) {
        int a = at * (TPB * QPT) + q * TPB + threadIdx.x;
        if (a < NA) {
            float best = fminf(best2[q].x, best2[q].y);   // exact fold
            out[a] = fmaxf(best + pn[q], 0.0f);
        }
    }
}

// ---------------------------------------------------------------------------
__device__ __forceinline__ void block_reduce2(float& s, float& cc, float* red) {
    int tid = threadIdx.x;
    red[tid] = s;
    red[RTPB + tid] = cc;
    __syncthreads();
    for (int o = RTPB / 2; o > 0; o >>= 1) {
        if (tid < o) {
            red[tid]        += red[tid + o];
            red[RTPB + tid] += red[RTPB + tid + o];
        }
        __syncthreads();
    }
    s  = red[0];
    cc = red[RTPB];
    __syncthreads();
}

__global__ void __launch_bounds__(RTPB) reduce_final_kernel(
    const float* __restrict__ minsplit,
    const int* __restrict__ label,
    float* __restrict__ pS, float* __restrict__ pC,
    unsigned int* __restrict__ counter,
    float* __restrict__ out,
    int B, int N, int M, int stride, int nblocks)
{
    __shared__ float red[2 * RTPB];
    const int r = blockIdx.x;

    const int dir = r / (B * CPB);
    const int rem = r - dir * (B * CPB);
    const int b   = rem / CPB;
    const int ch  = rem - b * CPB;
    const int NA  = dir ? M : N;
    const int qc  = (NA + CPB - 1) / CPB;          // queries per chunk
    const int qpt = (qc + RTPB - 1) / RTPB;        // queries per thread

    const float* base = minsplit + ((size_t)(dir * B + b) * SPLIT) * stride;

    float s = 0.0f, cc = 0.0f;
    for (int k = 0; k < qpt; ++k) {
        int q = ch * qc + k * RTPB + threadIdx.x;  // consecutive tid -> coalesced
        if (q < min((ch + 1) * qc, NA)) {
            float m = base[q];
#pragma unroll 8
            for (int sp = 1; sp < SPLIT; ++sp) {
                m = fminf(m, base[(size_t)sp * stride + q]);
            }
            if (dir == 0) {
                if (label[(size_t)b * N + q] == 1) { s += sqrtf(m); cc += 1.0f; }
            } else {
                s += sqrtf(m);
            }
        }
    }

    block_reduce2(s, cc, red);

    __shared__ unsigned int is_last;
    if (threadIdx.x == 0) {
        atomicExch(&pS[r], s);                 // device-scope, XCD-coherent
        atomicExch(&pC[r], cc);
        __threadfence();
        unsigned int old = atomicAdd(counter, 1u);
        is_last = (old == (unsigned int)(nblocks - 1)) ? 1u : 0u;
    }
    __syncthreads();

    if (is_last) {
        __shared__ float sS[2 * 64], sC[2 * 64];   // nblocks = 2*B*CPB <= 128
        for (int i = threadIdx.x; i < nblocks; i += RTPB) {
            sS[i] = atomicAdd(&pS[i], 0.0f);       // parallel device-scope reads
            sC[i] = atomicAdd(&pC[i], 0.0f);
        }
        __syncthreads();
        if (threadIdx.x == 0) {
            float acc = 0.0f;
            for (int bb = 0; bb < B; ++bb) {
                float S1 = 0.0f, C1 = 0.0f, S2 = 0.0f;
                for (int i = 0; i < CPB; ++i) {
                    S1 += sS[bb * CPB + i];
                    C1 += sC[bb * CPB + i];
                    S2 += sS[B * CPB + bb * CPB + i];
                }
                float m1 = S1 / fmaxf(C1, 1.0f);
                float m2 = S2 / (float)M;
                acc += 0.5f * (m1 + m2);
            }
            out[0] = acc / (float)B;   // * LOSS_WEIGHT (== 1.0)
        }
    }
}

// ---------------------------------------------------------------------------
extern "C" void kernel_launch(void* const* d_in, const int* in_sizes, int n_in,
                              void* d_out, int out_size, void* d_ws, size_t ws_size,
                              hipStream_t stream) {
    const float* pred   = (const float*)d_in[0];  // B*N*3 f32
    const float* target = (const float*)d_in[1];  // B*M*3 f32
    const int*   label  = (const int*)  d_in[2];  // B*N   i32

    const int B = in_sizes[3];                 // nums has shape (B,)
    const int N = in_sizes[2] / B;             // label is B*N
    const int M = in_sizes[1] / (3 * B);       // target is B*M*3

    const int stride = (N > M) ? N : M;

    // workspace layout (~4.2 MiB of the provided scratch)
    float* minsplit = (float*)d_ws;                               // 2*B*SPLIT*stride
    const int nred = 2 * B * CPB;                                 // 64 partials
    float* pS = minsplit + (size_t)2 * B * SPLIT * stride;        // nred
    float* pC = pS + nred;                                        // nred
    unsigned int* counter = (unsigned int*)(pC + nred);

    const int nat1 = (N + TPB * QPT - 1) / (TPB * QPT);
    const int nat2 = (M + TPB * QPT - 1) / (TPB * QPT);
    const int natmax = (nat1 > nat2) ? nat1 : nat2;
    dim3 g(B * natmax, SPLIT, 2);
    nn_kernel<<<g, TPB, 0, stream>>>(pred, target, label, minsplit, counter,
                                     B, N, M, natmax, stride);

    reduce_final_kernel<<<nred, RTPB, 0, stream>>>(minsplit, label, pS, pC,
                                                   counter, (float*)d_out,
                                                   B, N, M, stride, nred);
}